// Round 3
// baseline (629.943 us; speedup 1.0000x reference)
//
#include <hip/hip_runtime.h>
#include <hip/hip_bf16.h>
#include <math.h>

#define N_NODES 20000
#define F 128
#define NRBF 20
#define E_EDGES 320000
#define F3 (3 * F)   // 384
#define NCHUNK ((N_NODES + 255) / 256)   // 79

__device__ __forceinline__ float silu_f(float x) {
    return x / (1.0f + __expf(-x));
}

// ---------------------------------------------------------------------------
// Kernel A: per-node MLP -> bf16 filter planes.
//   h_s[n,f]        = (silu(s@W1+b1)@W2+b2)[f]          (s-channel)
//   h_v[n,f]        = packed bf16x2 {channel F+f, channel 2F+f}
// ---------------------------------------------------------------------------
#define NTILE_A 8
__global__ __launch_bounds__(128) void node_mlp_kernel(
    const float* __restrict__ s, const float* __restrict__ W1, const float* __restrict__ b1,
    const float* __restrict__ W2, const float* __restrict__ b2,
    __hip_bfloat16* __restrict__ h_s, __hip_bfloat162* __restrict__ h_v)
{
    __shared__ float sl[NTILE_A][F];
    __shared__ float hid[NTILE_A][F];
    const int g = threadIdx.x;
    const int n0 = blockIdx.x * NTILE_A;

    #pragma unroll
    for (int t = 0; t < NTILE_A; ++t)
        sl[t][g] = s[(size_t)(n0 + t) * F + g];
    __syncthreads();

    // stage 1: hid = silu(s @ W1 + b1), f unrolled by 4 with b128 LDS reads
    float acc[NTILE_A];
    #pragma unroll
    for (int t = 0; t < NTILE_A; ++t) acc[t] = 0.0f;
    for (int f = 0; f < F; f += 4) {
        float w0 = W1[(f + 0) * F + g];
        float w1 = W1[(f + 1) * F + g];
        float w2 = W1[(f + 2) * F + g];
        float w3 = W1[(f + 3) * F + g];
        #pragma unroll
        for (int t = 0; t < NTILE_A; ++t) {
            float4 sv = *(const float4*)&sl[t][f];
            acc[t] += sv.x * w0 + sv.y * w1 + sv.z * w2 + sv.w * w3;
        }
    }
    float bb = b1[g];
    #pragma unroll
    for (int t = 0; t < NTILE_A; ++t) hid[t][g] = silu_f(acc[t] + bb);
    __syncthreads();

    // stage 2: 3 output channels per thread, k unrolled by 4
    float a0[NTILE_A], a1[NTILE_A], a2[NTILE_A];
    #pragma unroll
    for (int t = 0; t < NTILE_A; ++t) { a0[t] = 0.0f; a1[t] = 0.0f; a2[t] = 0.0f; }

    for (int k = 0; k < F; k += 4) {
        float wA[4], wB[4], wC[4];
        #pragma unroll
        for (int kk = 0; kk < 4; ++kk) {
            wA[kk] = W2[(k + kk) * F3 + g];
            wB[kk] = W2[(k + kk) * F3 + F + g];
            wC[kk] = W2[(k + kk) * F3 + 2 * F + g];
        }
        #pragma unroll
        for (int t = 0; t < NTILE_A; ++t) {
            float4 hv = *(const float4*)&hid[t][k];
            a0[t] += hv.x * wA[0] + hv.y * wA[1] + hv.z * wA[2] + hv.w * wA[3];
            a1[t] += hv.x * wB[0] + hv.y * wB[1] + hv.z * wB[2] + hv.w * wB[3];
            a2[t] += hv.x * wC[0] + hv.y * wC[1] + hv.z * wC[2] + hv.w * wC[3];
        }
    }
    const float bs = b2[g], bvs = b2[F + g], bvv = b2[2 * F + g];
    #pragma unroll
    for (int t = 0; t < NTILE_A; ++t) {
        h_s[(size_t)(n0 + t) * F + g] = __float2bfloat16(a0[t] + bs);
        __hip_bfloat162 p;
        p.x = __float2bfloat16(a1[t] + bvs);
        p.y = __float2bfloat16(a2[t] + bvv);
        h_v[(size_t)(n0 + t) * F + g] = p;
    }
}

// ---------------------------------------------------------------------------
// cast v -> bf16 in d-major layout: v_bf[n*384 + d*128 + f] = v[n*384 + f*3 + d]
// ---------------------------------------------------------------------------
__global__ __launch_bounds__(256) void cast_v_kernel(const float* __restrict__ v,
                                                     __hip_bfloat16* __restrict__ v_bf)
{
    int tid = blockIdx.x * 256 + threadIdx.x;
    if (tid >= N_NODES * F3) return;
    int n = tid / F3;
    int r = tid - n * F3;
    int d = r >> 7;          // /128
    int f = r & 127;
    v_bf[tid] = __float2bfloat16(v[(size_t)n * F3 + f * 3 + d]);
}

// ---------------------------------------------------------------------------
// CSR build: histogram -> 3-phase scan -> scatter
// ---------------------------------------------------------------------------
__global__ __launch_bounds__(256) void hist_kernel(const int* __restrict__ i_index,
                                                   int* __restrict__ counts)
{
    int e = blockIdx.x * 256 + threadIdx.x;
    if (e < E_EDGES) atomicAdd(&counts[i_index[e]], 1);
}

__global__ __launch_bounds__(256) void scan_p1(const int* __restrict__ counts,
                                               int* __restrict__ row_start,
                                               int* __restrict__ chunk_sum)
{
    __shared__ int buf[256];
    const int tid = threadIdx.x;
    const int idx = blockIdx.x * 256 + tid;
    int val = (idx < N_NODES) ? counts[idx] : 0;
    buf[tid] = val;
    __syncthreads();
    for (int off = 1; off < 256; off <<= 1) {
        int t = (tid >= off) ? buf[tid - off] : 0;
        __syncthreads();
        buf[tid] += t;
        __syncthreads();
    }
    if (idx < N_NODES) row_start[idx] = buf[tid] - val;   // local exclusive
    if (tid == 255) chunk_sum[blockIdx.x] = buf[255];
}

__global__ __launch_bounds__(128) void scan_p2(const int* __restrict__ chunk_sum,
                                               int* __restrict__ chunk_off)
{
    __shared__ int buf[128];
    const int tid = threadIdx.x;
    int val = (tid < NCHUNK) ? chunk_sum[tid] : 0;
    buf[tid] = val;
    __syncthreads();
    for (int off = 1; off < 128; off <<= 1) {
        int t = (tid >= off) ? buf[tid - off] : 0;
        __syncthreads();
        buf[tid] += t;
        __syncthreads();
    }
    if (tid < NCHUNK) chunk_off[tid] = buf[tid] - val;    // exclusive
}

__global__ __launch_bounds__(256) void scan_p3(int* __restrict__ row_start,
                                               const int* __restrict__ chunk_off,
                                               int* __restrict__ cursor)
{
    int idx = blockIdx.x * 256 + threadIdx.x;
    if (idx < N_NODES) {
        int vv = row_start[idx] + chunk_off[blockIdx.x];
        row_start[idx] = vv;
        cursor[idx] = vv;
    }
    if (idx == 0) row_start[N_NODES] = E_EDGES;
}

__global__ __launch_bounds__(256) void scatter_kernel(const int* __restrict__ i_index,
                                                      int* __restrict__ cursor,
                                                      int* __restrict__ edge_ids)
{
    int e = blockIdx.x * 256 + threadIdx.x;
    if (e < E_EDGES) {
        int pos = atomicAdd(&cursor[i_index[e]], 1);
        edge_ids[pos] = e;
    }
}

// ---------------------------------------------------------------------------
// Kernel B: per-destination-node aggregation, bf16 gathers, no atomics.
//   s_agg fp32 [n][f];  v_agg fp32 d-major [n][d][f]
// ---------------------------------------------------------------------------
__global__ __launch_bounds__(128) void agg_kernel(
    const float* __restrict__ s, const float* __restrict__ v,
    const float* __restrict__ rbf, const float* __restrict__ dir,
    const int* __restrict__ j_index,
    const float* __restrict__ Wr, const float* __restrict__ br,
    const __hip_bfloat16* __restrict__ h_s, const __hip_bfloat162* __restrict__ h_v,
    const __hip_bfloat16* __restrict__ v_bf,
    const int* __restrict__ row_start, const int* __restrict__ edge_ids,
    float* __restrict__ s_agg, float* __restrict__ v_agg)
{
    const int f = threadIdx.x;
    const int n = blockIdx.x;

    float wr0[NRBF], wr1[NRBF], wr2[NRBF];
    #pragma unroll
    for (int k = 0; k < NRBF; ++k) {
        wr0[k] = Wr[k * F3 + f];
        wr1[k] = Wr[k * F3 + F + f];
        wr2[k] = Wr[k * F3 + 2 * F + f];
    }
    const float br0 = br[f], br1 = br[F + f], br2 = br[2 * F + f];

    float s_acc = s[(size_t)n * F + f];
    float v0 = v[(size_t)n * F3 + f * 3 + 0];
    float v1 = v[(size_t)n * F3 + f * 3 + 1];
    float v2 = v[(size_t)n * F3 + f * 3 + 2];

    const int beg = row_start[n];
    const int end = row_start[n + 1];
    const float cc = 0.6283185307179586f;   // pi/5

    for (int idx = beg; idx < end; ++idx) {
        const int e = edge_ids[idx];
        const int j = j_index[e];

        float x0 = br0, x1 = br1, x2 = br2;
        #pragma unroll
        for (int k = 0; k < NRBF; ++k) {
            float r = rbf[(size_t)e * NRBF + k];
            x0 += r * wr0[k];
            x1 += r * wr1[k];
            x2 += r * wr2[k];
        }
        float w0 = (x0 < 5.0f) ? 0.5f * (__cosf(x0 * cc) + 1.0f) : 0.0f;
        float w1 = (x1 < 5.0f) ? 0.5f * (__cosf(x1 * cc) + 1.0f) : 0.0f;
        float w2 = (x2 < 5.0f) ? 0.5f * (__cosf(x2 * cc) + 1.0f) : 0.0f;

        float hs  = __bfloat162float(h_s[(size_t)j * F + f]) * w0;
        __hip_bfloat162 hv = h_v[(size_t)j * F + f];
        float hvs = __bfloat162float(hv.x) * w1;
        float hvv = __bfloat162float(hv.y) * w2;

        float dx = dir[(size_t)e * 3 + 0];
        float dy = dir[(size_t)e * 3 + 1];
        float dz = dir[(size_t)e * 3 + 2];

        float vj0 = __bfloat162float(v_bf[(size_t)j * F3 + 0 * F + f]);
        float vj1 = __bfloat162float(v_bf[(size_t)j * F3 + 1 * F + f]);
        float vj2 = __bfloat162float(v_bf[(size_t)j * F3 + 2 * F + f]);

        s_acc += hs;
        v0 += hvs * dx + hvv * vj0;
        v1 += hvs * dy + hvv * vj1;
        v2 += hvs * dz + hvv * vj2;
    }

    s_agg[(size_t)n * F + f] = s_acc;
    v_agg[(size_t)n * F3 + 0 * F + f] = v0;   // d-major
    v_agg[(size_t)n * F3 + 1 * F + f] = v1;
    v_agg[(size_t)n * F3 + 2 * F + f] = v2;
}

// ---------------------------------------------------------------------------
// Kernel C: per-node update. v_agg is d-major fp32. T_C=8, vectorized LDS reads.
// ---------------------------------------------------------------------------
#define T_C 8
__global__ __launch_bounds__(128) void update_kernel(
    const float* __restrict__ s_agg, const float* __restrict__ v_agg,
    const float* __restrict__ WU, const float* __restrict__ bU,
    const float* __restrict__ WV, const float* __restrict__ bV,
    const float* __restrict__ M1, const float* __restrict__ bm1,
    const float* __restrict__ M2, const float* __restrict__ bm2,
    float* __restrict__ s_out, float* __restrict__ v_out)
{
    __shared__ float vl[T_C][3][F];     // d-major, same linear layout as v_agg
    __shared__ float inl[T_C][2 * F];   // [Vv_norm, s]
    __shared__ float hidl[T_C][F];

    const int g = threadIdx.x;
    const int n0 = blockIdx.x * T_C;

    for (int idx = g; idx < T_C * F3; idx += 128)
        ((float*)vl)[idx] = v_agg[(size_t)n0 * F3 + idx];
    #pragma unroll
    for (int t = 0; t < T_C; ++t)
        inl[t][F + g] = s_agg[(size_t)(n0 + t) * F + g];
    __syncthreads();

    // Uv / Vv: f unrolled by 2 (b64 LDS reads), 96 FMA per 4 weight floats
    float uacc[T_C][3], vacc[T_C][3];
    #pragma unroll
    for (int t = 0; t < T_C; ++t)
        #pragma unroll
        for (int d = 0; d < 3; ++d) { uacc[t][d] = 0.0f; vacc[t][d] = 0.0f; }

    for (int f = 0; f < F; f += 2) {
        float wu0 = WU[(f + 0) * F + g], wu1 = WU[(f + 1) * F + g];
        float wv0 = WV[(f + 0) * F + g], wv1 = WV[(f + 1) * F + g];
        #pragma unroll
        for (int t = 0; t < T_C; ++t) {
            #pragma unroll
            for (int d = 0; d < 3; ++d) {
                float2 vv = *(const float2*)&vl[t][d][f];
                uacc[t][d] += vv.x * wu0 + vv.y * wu1;
                vacc[t][d] += vv.x * wv0 + vv.y * wv1;
            }
        }
    }
    float bu = bU[g], bv = bV[g];
    #pragma unroll
    for (int t = 0; t < T_C; ++t) {
        #pragma unroll
        for (int d = 0; d < 3; ++d) { uacc[t][d] += bu; vacc[t][d] += bv; }
        inl[t][g] = sqrtf(vacc[t][0] * vacc[t][0] + vacc[t][1] * vacc[t][1] +
                          vacc[t][2] * vacc[t][2]);
    }
    __syncthreads();

    // MLP stage 1: k over 2F, unrolled by 4 (b128 LDS reads)
    float hacc[T_C];
    #pragma unroll
    for (int t = 0; t < T_C; ++t) hacc[t] = 0.0f;
    for (int k = 0; k < 2 * F; k += 4) {
        float m0 = M1[(k + 0) * F + g], m1 = M1[(k + 1) * F + g];
        float m2 = M1[(k + 2) * F + g], m3 = M1[(k + 3) * F + g];
        #pragma unroll
        for (int t = 0; t < T_C; ++t) {
            float4 iv = *(const float4*)&inl[t][k];
            hacc[t] += iv.x * m0 + iv.y * m1 + iv.z * m2 + iv.w * m3;
        }
    }
    float bh = bm1[g];
    #pragma unroll
    for (int t = 0; t < T_C; ++t) hidl[t][g] = silu_f(hacc[t] + bh);
    __syncthreads();

    // MLP stage 2: 3 outputs per thread, k unrolled by 2
    float ma[T_C], mb[T_C], mc[T_C];
    #pragma unroll
    for (int t = 0; t < T_C; ++t) { ma[t] = 0.0f; mb[t] = 0.0f; mc[t] = 0.0f; }
    for (int k = 0; k < F; k += 2) {
        float wA0 = M2[(k + 0) * F3 + g],         wA1 = M2[(k + 1) * F3 + g];
        float wB0 = M2[(k + 0) * F3 + F + g],     wB1 = M2[(k + 1) * F3 + F + g];
        float wC0 = M2[(k + 0) * F3 + 2 * F + g], wC1 = M2[(k + 1) * F3 + 2 * F + g];
        #pragma unroll
        for (int t = 0; t < T_C; ++t) {
            float2 hv = *(const float2*)&hidl[t][k];
            ma[t] += hv.x * wA0 + hv.y * wA1;
            mb[t] += hv.x * wB0 + hv.y * wB1;
            mc[t] += hv.x * wC0 + hv.y * wC1;
        }
    }
    const float bvv = bm2[g], bsv = bm2[F + g], bss = bm2[2 * F + g];

    #pragma unroll
    for (int t = 0; t < T_C; ++t) {
        float a_vv = ma[t] + bvv;
        float a_sv = mb[t] + bsv;
        float a_ss = mc[t] + bss;
        float dotuv = uacc[t][0] * vacc[t][0] + uacc[t][1] * vacc[t][1] +
                      uacc[t][2] * vacc[t][2];
        s_out[(size_t)(n0 + t) * F + g] = inl[t][F + g] + dotuv * a_sv + a_ss;
        #pragma unroll
        for (int d = 0; d < 3; ++d)
            v_out[(size_t)(n0 + t) * F3 + g * 3 + d] = vl[t][d][g] + a_vv * uacc[t][d];
    }
}

// ---------------------------------------------------------------------------
extern "C" void kernel_launch(void* const* d_in, const int* in_sizes, int n_in,
                              void* d_out, int out_size, void* d_ws, size_t ws_size,
                              hipStream_t stream) {
    const float* s    = (const float*)d_in[0];
    const float* v    = (const float*)d_in[1];
    const float* rbf  = (const float*)d_in[2];
    const float* dir  = (const float*)d_in[3];
    const float* W1   = (const float*)d_in[4];
    const float* b1   = (const float*)d_in[5];
    const float* W2   = (const float*)d_in[6];
    const float* b2   = (const float*)d_in[7];
    const float* Wr   = (const float*)d_in[8];
    const float* br   = (const float*)d_in[9];
    const float* WU   = (const float*)d_in[10];
    const float* bU   = (const float*)d_in[11];
    const float* WV   = (const float*)d_in[12];
    const float* bV   = (const float*)d_in[13];
    const float* M1   = (const float*)d_in[14];
    const float* bm1  = (const float*)d_in[15];
    const float* M2   = (const float*)d_in[16];
    const float* bm2  = (const float*)d_in[17];
    const int* i_index = (const int*)d_in[18];
    const int* j_index = (const int*)d_in[19];

    float* out_s = (float*)d_out;                     // N*F
    float* out_v = out_s + (size_t)N_NODES * F;       // N*F*3

    // workspace layout (fp32 arrays first, then bf16, then ints)
    char* w = (char*)d_ws;
    float* v_agg = (float*)w;                w += (size_t)N_NODES * F3 * 4;
    float* s_agg = (float*)w;                w += (size_t)N_NODES * F * 4;
    __hip_bfloat162* h_v = (__hip_bfloat162*)w;  w += (size_t)N_NODES * F * 4;
    __hip_bfloat16* h_s = (__hip_bfloat16*)w;    w += (size_t)N_NODES * F * 2;
    __hip_bfloat16* v_bf = (__hip_bfloat16*)w;   w += (size_t)N_NODES * F3 * 2;
    int* counts    = (int*)w;                w += (size_t)N_NODES * 4;
    int* row_start = (int*)w;                w += (size_t)(N_NODES + 1) * 4;
    int* cursor    = (int*)w;                w += (size_t)N_NODES * 4;
    int* edge_ids  = (int*)w;                w += (size_t)E_EDGES * 4;
    int* chunk_sum = (int*)w;                w += 128 * 4;
    int* chunk_off = (int*)w;

    hipMemsetAsync(counts, 0, sizeof(int) * N_NODES, stream);

    node_mlp_kernel<<<N_NODES / NTILE_A, 128, 0, stream>>>(s, W1, b1, W2, b2, h_s, h_v);
    cast_v_kernel<<<(N_NODES * F3 + 255) / 256, 256, 0, stream>>>(v, v_bf);

    hist_kernel<<<(E_EDGES + 255) / 256, 256, 0, stream>>>(i_index, counts);
    scan_p1<<<NCHUNK, 256, 0, stream>>>(counts, row_start, chunk_sum);
    scan_p2<<<1, 128, 0, stream>>>(chunk_sum, chunk_off);
    scan_p3<<<NCHUNK, 256, 0, stream>>>(row_start, chunk_off, cursor);
    scatter_kernel<<<(E_EDGES + 255) / 256, 256, 0, stream>>>(i_index, cursor, edge_ids);

    agg_kernel<<<N_NODES, 128, 0, stream>>>(s, v, rbf, dir, j_index, Wr, br,
                                            h_s, h_v, v_bf, row_start, edge_ids,
                                            s_agg, v_agg);

    update_kernel<<<N_NODES / T_C, 128, 0, stream>>>(s_agg, v_agg, WU, bU, WV, bV,
                                                     M1, bm1, M2, bm2, out_s, out_v);
}

// Round 4
// 574.629 us; speedup vs baseline: 1.0963x; 1.0963x over previous
//
#include <hip/hip_runtime.h>
#include <hip/hip_bf16.h>
#include <math.h>

#define N_NODES 20000
#define F 128
#define NRBF 20
#define E_EDGES 320000
#define F3 (3 * F)   // 384
#define NCHUNK ((N_NODES + 255) / 256)   // 79

__device__ __forceinline__ float silu_f(float x) {
    return x / (1.0f + __expf(-x));
}

// bf16 pack/unpack helpers (bf16 bits live in the upper 16 of the fp32 pattern)
__device__ __forceinline__ unsigned short f2bf(float x) {
    __hip_bfloat16 h = __float2bfloat16(x);
    return *(unsigned short*)&h;
}
__device__ __forceinline__ unsigned pack2(float a, float b) {
    return (unsigned)f2bf(a) | ((unsigned)f2bf(b) << 16);
}
__device__ __forceinline__ float bf_lo(unsigned u) { return __uint_as_float(u << 16); }
__device__ __forceinline__ float bf_hi(unsigned u) { return __uint_as_float(u & 0xffff0000u); }

// ---------------------------------------------------------------------------
// Kernel A: per-node MLP -> packed bf16 filter plane.
//   h_pack[n*F+f] = uint2{ pack(hs, hvs), pack(hvv, 0) }
// ---------------------------------------------------------------------------
#define NTILE_A 8
__global__ __launch_bounds__(128) void node_mlp_kernel(
    const float* __restrict__ s, const float* __restrict__ W1, const float* __restrict__ b1,
    const float* __restrict__ W2, const float* __restrict__ b2,
    uint2* __restrict__ h_pack)
{
    __shared__ float sl[NTILE_A][F];
    __shared__ float hid[NTILE_A][F];
    const int g = threadIdx.x;
    const int n0 = blockIdx.x * NTILE_A;

    #pragma unroll
    for (int t = 0; t < NTILE_A; ++t)
        sl[t][g] = s[(size_t)(n0 + t) * F + g];
    __syncthreads();

    float acc[NTILE_A];
    #pragma unroll
    for (int t = 0; t < NTILE_A; ++t) acc[t] = 0.0f;
    for (int f = 0; f < F; f += 4) {
        float w0 = W1[(f + 0) * F + g];
        float w1 = W1[(f + 1) * F + g];
        float w2 = W1[(f + 2) * F + g];
        float w3 = W1[(f + 3) * F + g];
        #pragma unroll
        for (int t = 0; t < NTILE_A; ++t) {
            float4 sv = *(const float4*)&sl[t][f];
            acc[t] += sv.x * w0 + sv.y * w1 + sv.z * w2 + sv.w * w3;
        }
    }
    float bb = b1[g];
    #pragma unroll
    for (int t = 0; t < NTILE_A; ++t) hid[t][g] = silu_f(acc[t] + bb);
    __syncthreads();

    float a0[NTILE_A], a1[NTILE_A], a2[NTILE_A];
    #pragma unroll
    for (int t = 0; t < NTILE_A; ++t) { a0[t] = 0.0f; a1[t] = 0.0f; a2[t] = 0.0f; }

    for (int k = 0; k < F; k += 4) {
        float wA[4], wB[4], wC[4];
        #pragma unroll
        for (int kk = 0; kk < 4; ++kk) {
            wA[kk] = W2[(k + kk) * F3 + g];
            wB[kk] = W2[(k + kk) * F3 + F + g];
            wC[kk] = W2[(k + kk) * F3 + 2 * F + g];
        }
        #pragma unroll
        for (int t = 0; t < NTILE_A; ++t) {
            float4 hv = *(const float4*)&hid[t][k];
            a0[t] += hv.x * wA[0] + hv.y * wA[1] + hv.z * wA[2] + hv.w * wA[3];
            a1[t] += hv.x * wB[0] + hv.y * wB[1] + hv.z * wB[2] + hv.w * wB[3];
            a2[t] += hv.x * wC[0] + hv.y * wC[1] + hv.z * wC[2] + hv.w * wC[3];
        }
    }
    const float bs = b2[g], bvs = b2[F + g], bvv = b2[2 * F + g];
    #pragma unroll
    for (int t = 0; t < NTILE_A; ++t) {
        h_pack[(size_t)(n0 + t) * F + g] =
            make_uint2(pack2(a0[t] + bs, a1[t] + bvs), pack2(a2[t] + bvv, 0.0f));
    }
}

// ---------------------------------------------------------------------------
// cast v -> packed bf16: v_pack[n*F+f] = uint2{ pack(v0,v1), pack(v2,0) }
// ---------------------------------------------------------------------------
__global__ __launch_bounds__(256) void cast_v_kernel(const float* __restrict__ v,
                                                     uint2* __restrict__ v_pack)
{
    int tid = blockIdx.x * 256 + threadIdx.x;
    if (tid >= N_NODES * F) return;
    int n = tid >> 7;
    int f = tid & 127;
    const float* vp = v + (size_t)n * F3 + f * 3;
    v_pack[tid] = make_uint2(pack2(vp[0], vp[1]), pack2(vp[2], 0.0f));
}

// ---------------------------------------------------------------------------
// CSR build: histogram -> 3-phase scan -> scatter
// ---------------------------------------------------------------------------
__global__ __launch_bounds__(256) void hist_kernel(const int* __restrict__ i_index,
                                                   int* __restrict__ counts)
{
    int e = blockIdx.x * 256 + threadIdx.x;
    if (e < E_EDGES) atomicAdd(&counts[i_index[e]], 1);
}

__global__ __launch_bounds__(256) void scan_p1(const int* __restrict__ counts,
                                               int* __restrict__ row_start,
                                               int* __restrict__ chunk_sum)
{
    __shared__ int buf[256];
    const int tid = threadIdx.x;
    const int idx = blockIdx.x * 256 + tid;
    int val = (idx < N_NODES) ? counts[idx] : 0;
    buf[tid] = val;
    __syncthreads();
    for (int off = 1; off < 256; off <<= 1) {
        int t = (tid >= off) ? buf[tid - off] : 0;
        __syncthreads();
        buf[tid] += t;
        __syncthreads();
    }
    if (idx < N_NODES) row_start[idx] = buf[tid] - val;
    if (tid == 255) chunk_sum[blockIdx.x] = buf[255];
}

__global__ __launch_bounds__(128) void scan_p2(const int* __restrict__ chunk_sum,
                                               int* __restrict__ chunk_off)
{
    __shared__ int buf[128];
    const int tid = threadIdx.x;
    int val = (tid < NCHUNK) ? chunk_sum[tid] : 0;
    buf[tid] = val;
    __syncthreads();
    for (int off = 1; off < 128; off <<= 1) {
        int t = (tid >= off) ? buf[tid - off] : 0;
        __syncthreads();
        buf[tid] += t;
        __syncthreads();
    }
    if (tid < NCHUNK) chunk_off[tid] = buf[tid] - val;
}

__global__ __launch_bounds__(256) void scan_p3(int* __restrict__ row_start,
                                               const int* __restrict__ chunk_off,
                                               int* __restrict__ cursor)
{
    int idx = blockIdx.x * 256 + threadIdx.x;
    if (idx < N_NODES) {
        int vv = row_start[idx] + chunk_off[blockIdx.x];
        row_start[idx] = vv;
        cursor[idx] = vv;
    }
    if (idx == 0) row_start[N_NODES] = E_EDGES;
}

__global__ __launch_bounds__(256) void scatter_kernel(const int* __restrict__ i_index,
                                                      int* __restrict__ cursor,
                                                      int* __restrict__ edge_ids)
{
    int e = blockIdx.x * 256 + threadIdx.x;
    if (e < E_EDGES) {
        int pos = atomicAdd(&cursor[i_index[e]], 1);
        edge_ids[pos] = e;
    }
}

// ---------------------------------------------------------------------------
// Kernel B: per-destination-node aggregation. 2×8B bf16 gathers per edge,
// scalarized uniform loads (e/j forced into SGPRs). Outputs written straight
// into d_out: s_agg = out_s [n][f], v_agg = out_v d-major [n][d][f].
// ---------------------------------------------------------------------------
__global__ __launch_bounds__(128) void agg_kernel(
    const float* __restrict__ s, const float* __restrict__ v,
    const float* __restrict__ rbf, const float* __restrict__ dir,
    const int* __restrict__ j_index,
    const float* __restrict__ Wr, const float* __restrict__ br,
    const uint2* __restrict__ h_pack, const uint2* __restrict__ v_pack,
    const int* __restrict__ row_start, const int* __restrict__ edge_ids,
    float* __restrict__ s_agg, float* __restrict__ v_agg)
{
    const int f = threadIdx.x;
    const int n = blockIdx.x;

    float wr0[NRBF], wr1[NRBF], wr2[NRBF];
    #pragma unroll
    for (int k = 0; k < NRBF; ++k) {
        wr0[k] = Wr[k * F3 + f];
        wr1[k] = Wr[k * F3 + F + f];
        wr2[k] = Wr[k * F3 + 2 * F + f];
    }
    const float br0 = br[f], br1 = br[F + f], br2 = br[2 * F + f];

    float s_acc = s[(size_t)n * F + f];
    float v0 = v[(size_t)n * F3 + f * 3 + 0];
    float v1 = v[(size_t)n * F3 + f * 3 + 1];
    float v2 = v[(size_t)n * F3 + f * 3 + 2];

    const int beg = row_start[n];
    const int end = row_start[n + 1];
    const float cc = 0.6283185307179586f;   // pi/5

    for (int idx = beg; idx < end; ++idx) {
        // e and j are uniform across the block; force into SGPRs so the
        // rbf/dir reads compile to s_load instead of 64-lane vector loads.
        const int e = __builtin_amdgcn_readfirstlane(edge_ids[idx]);
        const int j = __builtin_amdgcn_readfirstlane(j_index[e]);

        float x0 = br0, x1 = br1, x2 = br2;
        #pragma unroll
        for (int k = 0; k < NRBF; ++k) {
            float r = rbf[(size_t)e * NRBF + k];
            x0 += r * wr0[k];
            x1 += r * wr1[k];
            x2 += r * wr2[k];
        }
        float w0 = (x0 < 5.0f) ? 0.5f * (__cosf(x0 * cc) + 1.0f) : 0.0f;
        float w1 = (x1 < 5.0f) ? 0.5f * (__cosf(x1 * cc) + 1.0f) : 0.0f;
        float w2 = (x2 < 5.0f) ? 0.5f * (__cosf(x2 * cc) + 1.0f) : 0.0f;

        uint2 hp = h_pack[(size_t)j * F + f];
        float hs  = bf_lo(hp.x) * w0;
        float hvs = bf_hi(hp.x) * w1;
        float hvv = bf_lo(hp.y) * w2;

        float dx = dir[(size_t)e * 3 + 0];
        float dy = dir[(size_t)e * 3 + 1];
        float dz = dir[(size_t)e * 3 + 2];

        uint2 vp = v_pack[(size_t)j * F + f];
        float vj0 = bf_lo(vp.x);
        float vj1 = bf_hi(vp.x);
        float vj2 = bf_lo(vp.y);

        s_acc += hs;
        v0 += hvs * dx + hvv * vj0;
        v1 += hvs * dy + hvv * vj1;
        v2 += hvs * dz + hvv * vj2;
    }

    s_agg[(size_t)n * F + f] = s_acc;
    v_agg[(size_t)n * F3 + 0 * F + f] = v0;   // d-major
    v_agg[(size_t)n * F3 + 1 * F + f] = v1;
    v_agg[(size_t)n * F3 + 2 * F + f] = v2;
}

// ---------------------------------------------------------------------------
// Kernel C: per-node update — R2 structure (T_C=4), d-major v_agg.
// Reads s_agg/v_agg from d_out and rewrites the same rows in place (each
// block fully stages its rows into LDS before writing).
// ---------------------------------------------------------------------------
#define T_C 4
__global__ __launch_bounds__(128) void update_kernel(
    const float* __restrict__ s_agg, const float* __restrict__ v_agg,
    const float* __restrict__ WU, const float* __restrict__ bU,
    const float* __restrict__ WV, const float* __restrict__ bV,
    const float* __restrict__ M1, const float* __restrict__ bm1,
    const float* __restrict__ M2, const float* __restrict__ bm2,
    float* __restrict__ s_out, float* __restrict__ v_out)
{
    __shared__ float vl[T_C][3][F];     // d-major
    __shared__ float inl[T_C][2 * F];   // [Vv_norm, s]
    __shared__ float hidl[T_C][F];

    const int g = threadIdx.x;
    const int n0 = blockIdx.x * T_C;

    for (int idx = g; idx < T_C * F3; idx += 128)
        ((float*)vl)[idx] = v_agg[(size_t)n0 * F3 + idx];
    #pragma unroll
    for (int t = 0; t < T_C; ++t)
        inl[t][F + g] = s_agg[(size_t)(n0 + t) * F + g];
    __syncthreads();

    float uacc[T_C][3], vacc[T_C][3];
    #pragma unroll
    for (int t = 0; t < T_C; ++t)
        #pragma unroll
        for (int d = 0; d < 3; ++d) { uacc[t][d] = 0.0f; vacc[t][d] = 0.0f; }

    for (int f = 0; f < F; ++f) {
        float wu = WU[f * F + g];
        float wv = WV[f * F + g];
        #pragma unroll
        for (int t = 0; t < T_C; ++t) {
            #pragma unroll
            for (int d = 0; d < 3; ++d) {
                float vv = vl[t][d][f];
                uacc[t][d] += vv * wu;
                vacc[t][d] += vv * wv;
            }
        }
    }
    float bu = bU[g], bv = bV[g];
    #pragma unroll
    for (int t = 0; t < T_C; ++t) {
        #pragma unroll
        for (int d = 0; d < 3; ++d) { uacc[t][d] += bu; vacc[t][d] += bv; }
        inl[t][g] = sqrtf(vacc[t][0] * vacc[t][0] + vacc[t][1] * vacc[t][1] +
                          vacc[t][2] * vacc[t][2]);
    }
    __syncthreads();

    float hacc[T_C];
    #pragma unroll
    for (int t = 0; t < T_C; ++t) hacc[t] = 0.0f;
    for (int k = 0; k < 2 * F; ++k) {
        float m1 = M1[k * F + g];
        #pragma unroll
        for (int t = 0; t < T_C; ++t) hacc[t] += inl[t][k] * m1;
    }
    float bh = bm1[g];
    #pragma unroll
    for (int t = 0; t < T_C; ++t) hidl[t][g] = silu_f(hacc[t] + bh);
    __syncthreads();

    float macc[3][T_C];
    #pragma unroll
    for (int o3 = 0; o3 < 3; ++o3)
        #pragma unroll
        for (int t = 0; t < T_C; ++t) macc[o3][t] = 0.0f;
    for (int k = 0; k < F; ++k) {
        #pragma unroll
        for (int o3 = 0; o3 < 3; ++o3) {
            float m2 = M2[k * F3 + o3 * F + g];
            #pragma unroll
            for (int t = 0; t < T_C; ++t) macc[o3][t] += hidl[t][k] * m2;
        }
    }
    const float bvv = bm2[g], bsv = bm2[F + g], bss = bm2[2 * F + g];

    #pragma unroll
    for (int t = 0; t < T_C; ++t) {
        float a_vv = macc[0][t] + bvv;
        float a_sv = macc[1][t] + bsv;
        float a_ss = macc[2][t] + bss;
        float dotuv = uacc[t][0] * vacc[t][0] + uacc[t][1] * vacc[t][1] +
                      uacc[t][2] * vacc[t][2];
        s_out[(size_t)(n0 + t) * F + g] = inl[t][F + g] + dotuv * a_sv + a_ss;
        #pragma unroll
        for (int d = 0; d < 3; ++d)
            v_out[(size_t)(n0 + t) * F3 + g * 3 + d] = vl[t][d][g] + a_vv * uacc[t][d];
    }
}

// ---------------------------------------------------------------------------
extern "C" void kernel_launch(void* const* d_in, const int* in_sizes, int n_in,
                              void* d_out, int out_size, void* d_ws, size_t ws_size,
                              hipStream_t stream) {
    const float* s    = (const float*)d_in[0];
    const float* v    = (const float*)d_in[1];
    const float* rbf  = (const float*)d_in[2];
    const float* dir  = (const float*)d_in[3];
    const float* W1   = (const float*)d_in[4];
    const float* b1   = (const float*)d_in[5];
    const float* W2   = (const float*)d_in[6];
    const float* b2   = (const float*)d_in[7];
    const float* Wr   = (const float*)d_in[8];
    const float* br   = (const float*)d_in[9];
    const float* WU   = (const float*)d_in[10];
    const float* bU   = (const float*)d_in[11];
    const float* WV   = (const float*)d_in[12];
    const float* bV   = (const float*)d_in[13];
    const float* M1   = (const float*)d_in[14];
    const float* bm1  = (const float*)d_in[15];
    const float* M2   = (const float*)d_in[16];
    const float* bm2  = (const float*)d_in[17];
    const int* i_index = (const int*)d_in[18];
    const int* j_index = (const int*)d_in[19];

    float* out_s = (float*)d_out;                     // N*F ; doubles as s_agg
    float* out_v = out_s + (size_t)N_NODES * F;       // N*F*3 ; doubles as v_agg (d-major)

    // workspace
    char* w = (char*)d_ws;
    uint2* h_pack = (uint2*)w;   w += (size_t)N_NODES * F * 8;
    uint2* v_pack = (uint2*)w;   w += (size_t)N_NODES * F * 8;
    int* counts    = (int*)w;    w += (size_t)N_NODES * 4;
    int* row_start = (int*)w;    w += (size_t)(N_NODES + 1) * 4;
    int* cursor    = (int*)w;    w += (size_t)N_NODES * 4;
    int* edge_ids  = (int*)w;    w += (size_t)E_EDGES * 4;
    int* chunk_sum = (int*)w;    w += 128 * 4;
    int* chunk_off = (int*)w;

    hipMemsetAsync(counts, 0, sizeof(int) * N_NODES, stream);

    node_mlp_kernel<<<N_NODES / NTILE_A, 128, 0, stream>>>(s, W1, b1, W2, b2, h_pack);
    cast_v_kernel<<<(N_NODES * F + 255) / 256, 256, 0, stream>>>(v, v_pack);

    hist_kernel<<<(E_EDGES + 255) / 256, 256, 0, stream>>>(i_index, counts);
    scan_p1<<<NCHUNK, 256, 0, stream>>>(counts, row_start, chunk_sum);
    scan_p2<<<1, 128, 0, stream>>>(chunk_sum, chunk_off);
    scan_p3<<<NCHUNK, 256, 0, stream>>>(row_start, chunk_off, cursor);
    scatter_kernel<<<(E_EDGES + 255) / 256, 256, 0, stream>>>(i_index, cursor, edge_ids);

    agg_kernel<<<N_NODES, 128, 0, stream>>>(s, v, rbf, dir, j_index, Wr, br,
                                            h_pack, v_pack, row_start, edge_ids,
                                            out_s, out_v);

    update_kernel<<<N_NODES / T_C, 128, 0, stream>>>(out_s, out_v, WU, bU, WV, bV,
                                                     M1, bm1, M2, bm2, out_s, out_v);
}